// Round 2
// baseline (923.059 us; speedup 1.0000x reference)
//
#include <hip/hip_runtime.h>

#define EPS 1e-4f
#define D 64
#define NCASES 8

// ---------------------------------------------------------------------------
// Kernel 1: precompute W_sum (64x64) and b_sum (64) into workspace.
// ws layout: [0..4095] = W_sum (row-major i*64+j), [4096..4159] = b_sum.
// ---------------------------------------------------------------------------
__global__ void prep_sums(const float* __restrict__ W, const float* __restrict__ b,
                          float* __restrict__ ws) {
  int idx = blockIdx.x * blockDim.x + threadIdx.x;
  if (idx < D * D) {
    float s = 0.f;
#pragma unroll
    for (int c = 0; c < NCASES; ++c) s += W[c * D * D + idx];
    ws[idx] = s;
  } else if (idx < D * D + D) {
    int j = idx - D * D;
    float s = 0.f;
#pragma unroll
    for (int c = 0; c < NCASES; ++c) s += b[c * D + j];
    ws[idx] = s;
  }
}

// ---------------------------------------------------------------------------
// Kernel 2: one WAVE per row, lane = output column.
//   - wv[i] = Wsum[i][lane] register-resident (64 VGPRs), loaded once/wave.
//   - x row + presence via wave-uniform pointer -> scalar loads (s_load),
//     so the hot FMA is v_fma_f32 acc, s_x, v_w with zero LDS traffic.
//   - x, presence, out accesses all coalesced.
// Rare path (~8e-4 of rows): subtract inactive-case contributions.
// ---------------------------------------------------------------------------
__global__ __launch_bounds__(256, 4) void guarded_layer(
    const float* __restrict__ x, const float* __restrict__ presence,
    const float* __restrict__ W, const float* __restrict__ b,
    const float* __restrict__ Wsum, const float* __restrict__ bsum,
    float* __restrict__ out, int N) {
  const int lane = threadIdx.x & 63;
  const int wid = (blockIdx.x * blockDim.x + threadIdx.x) >> 6;
  const int nwaves = (gridDim.x * blockDim.x) >> 6;

  // Register-resident Wsum column slice: 64 VGPRs/lane. Coalesced loads,
  // L2-hot after the first wave; amortized over ~128 rows per wave.
  float wv[D];
#pragma unroll
  for (int i = 0; i < D; ++i) wv[i] = Wsum[i * D + lane];
  const float bs = bsum[lane];

  for (int r = wid; r < N; r += nwaves) {
    // Force wave-uniformity so x/presence row loads become s_load.
    const int ur = __builtin_amdgcn_readfirstlane(r);
    const float* __restrict__ xr = x + (size_t)ur * D;
    const float* __restrict__ pr = presence + (size_t)ur * NCASES;

    // 4 partial accumulators break the 64-deep FMA dependency chain.
    float a0 = bs, a1 = 0.f, a2 = 0.f, a3 = 0.f;
#pragma unroll
    for (int i = 0; i < D; i += 4) {
      a0 = fmaf(xr[i + 0], wv[i + 0], a0);
      a1 = fmaf(xr[i + 1], wv[i + 1], a1);
      a2 = fmaf(xr[i + 2], wv[i + 2], a2);
      a3 = fmaf(xr[i + 3], wv[i + 3], a3);
    }
    float acc = (a0 + a1) + (a2 + a3);

    // All-active check (wave-uniform branch; scalar presence values).
    bool allact = true;
#pragma unroll
    for (int c = 0; c < NCASES; ++c) allact = allact && (pr[c] > EPS);

    if (!allact) {
      // ~0.08% of rows: subtract x@W_c + b_c for each inactive case.
#pragma unroll 1
      for (int c = 0; c < NCASES; ++c) {
        if (!(pr[c] > EPS)) {
          float corr = b[c * D + lane];
          const float* __restrict__ Wc = W + (size_t)c * D * D;
#pragma unroll 1
          for (int i = 0; i < D; ++i)
            corr = fmaf(xr[i], Wc[i * D + lane], corr);
          acc -= corr;
        }
      }
    }

    out[(size_t)ur * D + lane] = acc;  // coalesced 256 B/wave store
  }
}

extern "C" void kernel_launch(void* const* d_in, const int* in_sizes, int n_in,
                              void* d_out, int out_size, void* d_ws, size_t ws_size,
                              hipStream_t stream) {
  const float* x = (const float*)d_in[0];
  const float* presence = (const float*)d_in[1];
  const float* W = (const float*)d_in[2];
  const float* b = (const float*)d_in[3];
  float* out = (float*)d_out;
  float* ws = (float*)d_ws;

  int N = in_sizes[0] / D;

  prep_sums<<<(D * D + D + 255) / 256, 256, 0, stream>>>(W, b, ws);

  // 2048 blocks x 4 waves = 8192 waves; 1M rows -> 128 rows/wave grid-stride.
  guarded_layer<<<2048, 256, 0, stream>>>(
      x, presence, W, b, ws, ws + D * D, out, N);
}

// Round 3
// 598.799 us; speedup vs baseline: 1.5415x; 1.5415x over previous
//
#include <hip/hip_runtime.h>

#define EPS 1e-4f
#define D 64
#define NCASES 8
#define ROWS 128          // rows per block/tile
#define RS (ROWS + 1)     // padded lane-stride (words) in LDS: banks conflict-free

// ---------------------------------------------------------------------------
// Kernel 1: precompute W_sum (64x64) and b_sum (64) into workspace.
// ws layout: [0..4095] = W_sum (row-major k*64+j), [4096..4159] = b_sum.
// ---------------------------------------------------------------------------
__global__ void prep_sums(const float* __restrict__ W, const float* __restrict__ b,
                          float* __restrict__ ws) {
  int idx = blockIdx.x * blockDim.x + threadIdx.x;
  if (idx < D * D) {
    float s = 0.f;
#pragma unroll
    for (int c = 0; c < NCASES; ++c) s += W[c * D * D + idx];
    ws[idx] = s;
  } else if (idx < D * D + D) {
    int j = idx - D * D;
    float s = 0.f;
#pragma unroll
    for (int c = 0; c < NCASES; ++c) s += b[c * D + j];
    ws[idx] = s;
  }
}

// ---------------------------------------------------------------------------
// Kernel 2: block = 128 threads = 128 rows. Thread r owns row r of the tile.
//  1) stage x tile TRANSPOSED+padded into LDS (coalesced global, bank-free LDS)
//  2) acc[j] = bsum[j] + sum_k xT[k][r] * Wsum[k][j]   (Wsum wave-uniform;
//     16KB re-streamed once per 64 rows -> <=256MB L2 total, negligible)
//  3) rare (~8e-4 rows) exec-masked correction for inactive cases
//  4) flush acc through LDS -> coalesced float4 stores
// ---------------------------------------------------------------------------
__global__ __launch_bounds__(128, 2) void guarded_layer(
    const float* __restrict__ x, const float* __restrict__ presence,
    const float* __restrict__ W, const float* __restrict__ b,
    const float* __restrict__ Wsum, const float* __restrict__ bsum,
    float* __restrict__ out, int N) {
  __shared__ float xT[D * RS];  // xT[k*RS + r]; reused for output transpose

  const int t = threadIdx.x;          // 0..127
  const long long row0 = (long long)blockIdx.x * ROWS;
  const int r = t;                    // my row within the tile
  const long long myrow = row0 + r;

  // ---- stage x tile transposed (16 float4 per thread, coalesced) ----
  const float4* __restrict__ xg = reinterpret_cast<const float4*>(x) + row0 * (D / 4);
#pragma unroll
  for (int q = 0; q < 16; ++q) {
    int f = t + 128 * q;              // float4 index within the 128x64 tile
    int R = f >> 4;                   // tile row
    int C = (f & 15) << 2;            // starting col
    long long gr = row0 + R;
    float4 v = xg[gr < N ? f : 0];    // clamp (tail-safe; N divisible -> no-op)
    xT[(C + 0) * RS + R] = v.x;
    xT[(C + 1) * RS + R] = v.y;
    xT[(C + 2) * RS + R] = v.z;
    xT[(C + 3) * RS + R] = v.w;
  }

  // presence for my row (independent of LDS; issue before barrier)
  const float4* __restrict__ pg =
      reinterpret_cast<const float4*>(presence) + (myrow < N ? myrow : 0) * (NCASES / 4);
  float4 p0 = pg[0];
  float4 p1 = pg[1];

  __syncthreads();

  // ---- main matvec: acc[j] over my row ----
  float acc[D];
#pragma unroll
  for (int j = 0; j < D; ++j) acc[j] = bsum[j];

#pragma unroll 1
  for (int k0 = 0; k0 < D; k0 += 8) {
    float xk[8];
#pragma unroll
    for (int kk = 0; kk < 8; ++kk) xk[kk] = xT[(k0 + kk) * RS + r];
#pragma unroll
    for (int kk = 0; kk < 8; ++kk) {
      const float* __restrict__ wr = Wsum + (size_t)(k0 + kk) * D;  // uniform
#pragma unroll
      for (int j = 0; j < D; ++j) acc[j] = fmaf(xk[kk], wr[j], acc[j]);
    }
  }

  // ---- rare correction: subtract x@W_c + b_c for inactive cases ----
  bool allact = (p0.x > EPS) & (p0.y > EPS) & (p0.z > EPS) & (p0.w > EPS) &
                (p1.x > EPS) & (p1.y > EPS) & (p1.z > EPS) & (p1.w > EPS);
  if (__builtin_expect(!allact, 0)) {
    float pv[NCASES] = {p0.x, p0.y, p0.z, p0.w, p1.x, p1.y, p1.z, p1.w};
#pragma unroll 1
    for (int c = 0; c < NCASES; ++c) {
      if (!(pv[c] > EPS)) {
        const float* __restrict__ bc = b + c * D;
#pragma unroll
        for (int j = 0; j < D; ++j) acc[j] -= bc[j];
        const float* __restrict__ Wc = W + (size_t)c * D * D;
#pragma unroll 1
        for (int k = 0; k < D; ++k) {
          float xk = xT[k * RS + r];
#pragma unroll
          for (int j = 0; j < D; ++j) acc[j] = fmaf(-xk, Wc[k * D + j], acc[j]);
        }
      }
    }
  }

  // ---- transpose acc through LDS, then coalesced float4 stores ----
  __syncthreads();  // everyone done reading xT
#pragma unroll
  for (int j = 0; j < D; ++j) xT[j * RS + r] = acc[j];
  __syncthreads();

  float4* __restrict__ og = reinterpret_cast<float4*>(out) + row0 * (D / 4);
#pragma unroll
  for (int q = 0; q < 16; ++q) {
    int f = t + 128 * q;
    int R = f >> 4;
    int C = (f & 15) << 2;
    if (row0 + R < N) {
      float4 v;
      v.x = xT[(C + 0) * RS + R];
      v.y = xT[(C + 1) * RS + R];
      v.z = xT[(C + 2) * RS + R];
      v.w = xT[(C + 3) * RS + R];
      og[f] = v;
    }
  }
}

extern "C" void kernel_launch(void* const* d_in, const int* in_sizes, int n_in,
                              void* d_out, int out_size, void* d_ws, size_t ws_size,
                              hipStream_t stream) {
  const float* x = (const float*)d_in[0];
  const float* presence = (const float*)d_in[1];
  const float* W = (const float*)d_in[2];
  const float* b = (const float*)d_in[3];
  float* out = (float*)d_out;
  float* ws = (float*)d_ws;

  int N = in_sizes[0] / D;

  prep_sums<<<(D * D + D + 255) / 256, 256, 0, stream>>>(W, b, ws);

  int nblocks = (N + ROWS - 1) / ROWS;  // 8192 for N=1M
  guarded_layer<<<nblocks, ROWS, 0, stream>>>(
      x, presence, W, b, ws, ws + D * D, out, N);
}